// Round 2
// baseline (15916.151 us; speedup 1.0000x reference)
//
#include <hip/hip_runtime.h>

#define BB 64   // batch
#define CC 64   // channels

// ================= Kernel A: GN1 stats directly from x (recompute conv1) =================
// grid (8, BB), block 256. Block handles 16 of 128 output rows (2 strips of 8).
// Writes partial sums ps/ps2[(b*8+qq)*64 + c].
__global__ __launch_bounds__(256) void conv1stats_kernel(const float* __restrict__ x,
    const float* __restrict__ w1, const float* __restrict__ b1,
    float* __restrict__ ps, float* __restrict__ ps2) {
    __shared__ float sw1[576];
    __shared__ float sb1[64];
    __shared__ float xs[10 * 130];
    int tid = threadIdx.x;
    int qq = blockIdx.x;
    int b = blockIdx.y;
    for (int i = tid; i < 576; i += 256) sw1[i] = w1[i];
    if (tid < 64) sb1[tid] = b1[tid];
    const float* xb = x + (size_t)b * 130 * 130;
    int c = tid >> 2, q = tid & 3;
    float s = 0.f, s2 = 0.f;
    for (int sidx = 0; sidx < 2; sidx++) {
        int row0 = (qq * 2 + sidx) * 8;           // output row base; x rows row0..row0+9
        __syncthreads();
        for (int i = tid; i < 1300; i += 256) xs[i] = xb[row0 * 130 + i];
        __syncthreads();
        const float* wc = &sw1[c * 9];
        float bc = sb1[c];
        for (int p = q; p < 1024; p += 4) {
            int y = p >> 7, xx = p & 127;
            float v = bc;
#pragma unroll
            for (int ky = 0; ky < 3; ky++)
#pragma unroll
                for (int kx = 0; kx < 3; kx++)
                    v += xs[(y + ky) * 130 + xx + kx] * wc[ky * 3 + kx];
            s += v; s2 += v * v;
        }
    }
    s  += __shfl_xor(s, 1, 64);  s  += __shfl_xor(s, 2, 64);
    s2 += __shfl_xor(s2, 1, 64); s2 += __shfl_xor(s2, 2, 64);
    if (q == 0) {
        ps [(b * 8 + qq) * 64 + c] = s;
        ps2[(b * 8 + qq) * 64 + c] = s2;
    }
}

// ================= Kernel A2: combine partials -> per-(b,c) scale/shift =================
__global__ __launch_bounds__(256) void gn1fin_kernel(const float* __restrict__ ps,
    const float* __restrict__ ps2, const float* __restrict__ n1w, const float* __restrict__ n1b,
    float* __restrict__ gn1sc, float* __restrict__ gn1sh) {
    int i = blockIdx.x * 256 + threadIdx.x;   // [0,4096)
    if (i >= BB * CC) return;
    int b = i >> 6, c = i & 63;
    float s = 0.f, s2 = 0.f;
#pragma unroll
    for (int qq = 0; qq < 8; qq++) {
        s  += ps [(b * 8 + qq) * 64 + c];
        s2 += ps2[(b * 8 + qq) * 64 + c];
    }
    float mean = s / 16384.f;
    float var = s2 / 16384.f - mean * mean;
    float rstd = rsqrtf(var + 1e-5f);
    float sc = rstd * n1w[c];
    gn1sc[i] = sc;
    gn1sh[i] = n1b[c] - mean * sc;
}

// ================= Kernel B: fused conv1 + GN1 + ReLU + conv4x4/s2 -> h2[B,64,64,64] ====
// grid (16 tiles, 8 cog, BB), block 256 (16x16 out pixels, 8 c_out each).
__global__ __launch_bounds__(256) void fusedconv2_kernel(const float* __restrict__ x,
    const float* __restrict__ w1, const float* __restrict__ b1,
    const float* __restrict__ gn1sc, const float* __restrict__ gn1sh,
    const float* __restrict__ w2, const float* __restrict__ bias2, float* __restrict__ out) {
    __shared__ float swt[8 * 64 * 16];   // 32 KB
    __shared__ float sw1[576];
    __shared__ float sb1[64];
    __shared__ float ssc[64];
    __shared__ float ssh[64];
    __shared__ float xs[36 * 36];
    __shared__ float stile[34 * 34];
    int tid = threadIdx.x;
    int b = blockIdx.z, cog = blockIdx.y, tile = blockIdx.x;
    int tx0 = (tile & 3) * 16, ty0 = (tile >> 2) * 16;
    const float* wp = w2 + (size_t)cog * 8 * 64 * 16;
    for (int i = tid; i < 8192; i += 256) swt[i] = wp[i];
    for (int i = tid; i < 576; i += 256) sw1[i] = w1[i];
    if (tid < 64) {
        sb1[tid] = b1[tid];
        ssc[tid] = gn1sc[b * 64 + tid];
        ssh[tid] = gn1sh[b * 64 + tid];
    }
    {   // stage x halo region 36x36 (x rows/cols 2*t0-1 .. 2*t0+34)
        const float* xb = x + (size_t)b * 130 * 130;
        for (int i = tid; i < 1296; i += 256) {
            int r = i / 36, cc = i % 36;
            int gr = 2 * ty0 - 1 + r, gc = 2 * tx0 - 1 + cc;
            xs[i] = (gr >= 0 && gr < 130 && gc >= 0 && gc < 130) ? xb[gr * 130 + gc] : 0.f;
        }
    }
    int tx = tid & 15, ty = tid >> 4;
    float acc[8];
#pragma unroll
    for (int i = 0; i < 8; i++) acc[i] = 0.f;
    __syncthreads();
    for (int ci = 0; ci < 64; ci++) {
        // build normalized h1 tile (34x34, zero-padded) for channel ci
        float csc = ssc[ci], csh = ssh[ci], cb = sb1[ci];
        const float* wc1 = &sw1[ci * 9];
        for (int i = tid; i < 1156; i += 256) {
            int r = i / 34, cc = i % 34;
            int gy = 2 * ty0 - 1 + r, gx = 2 * tx0 - 1 + cc;
            float v = 0.f;
            if (gy >= 0 && gy < 128 && gx >= 0 && gx < 128) {
                float sacc = cb;
#pragma unroll
                for (int ky = 0; ky < 3; ky++)
#pragma unroll
                    for (int kx = 0; kx < 3; kx++)
                        sacc += xs[(r + ky) * 36 + cc + kx] * wc1[ky * 3 + kx];
                v = fmaxf(fmaf(sacc, csc, csh), 0.f);
            }
            stile[i] = v;
        }
        __syncthreads();
        float tv[16];
#pragma unroll
        for (int ky = 0; ky < 4; ky++)
#pragma unroll
            for (int kx = 0; kx < 4; kx++)
                tv[ky * 4 + kx] = stile[(2 * ty + ky) * 34 + 2 * tx + kx];
#pragma unroll
        for (int co = 0; co < 8; co++) {
            const float* wc = &swt[(co * 64 + ci) * 16];
            float a = acc[co];
#pragma unroll
            for (int k = 0; k < 16; k++) a += tv[k] * wc[k];
            acc[co] = a;
        }
        __syncthreads();
    }
    int oy = ty0 + ty, ox = tx0 + tx;
    float* ob = out + (size_t)b * 64 * 4096 + (size_t)(cog * 8) * 4096 + (size_t)oy * 64 + ox;
#pragma unroll
    for (int co = 0; co < 8; co++)
        ob[(size_t)co * 4096] = acc[co] + bias2[cog * 8 + co];
}

// ================= conv 4x4 stride2 pad1, 64->64, HOUT=32 (h2 -> z) =================
template<int HOUT>
__global__ __launch_bounds__(256) void conv4s2_kernel(const float* __restrict__ in,
    const float* __restrict__ w, const float* __restrict__ bias, float* __restrict__ out) {
    const int HIN = 2 * HOUT;
    const int TILES = HOUT / 16;
    __shared__ float swt[8 * 64 * 16];
    __shared__ float stile[34 * 34];
    int tid = threadIdx.x;
    int b = blockIdx.z;
    int cog = blockIdx.y;
    int tileid = blockIdx.x;
    int tx0 = (tileid % TILES) * 16;
    int ty0 = (tileid / TILES) * 16;
    const float* wp = w + (size_t)cog * 8 * 64 * 16;
    for (int i = tid; i < 8192; i += 256) swt[i] = wp[i];
    int tx = tid & 15, ty = tid >> 4;
    float acc[8];
#pragma unroll
    for (int i = 0; i < 8; i++) acc[i] = 0.f;
    const float* ib = in + (size_t)b * 64 * HIN * HIN;
    for (int ci = 0; ci < 64; ci++) {
        __syncthreads();
        const float* ip = ib + (size_t)ci * HIN * HIN;
        for (int i = tid; i < 1156; i += 256) {
            int r = i / 34, cc = i % 34;
            int gy = 2 * ty0 - 1 + r, gx = 2 * tx0 - 1 + cc;
            float v = 0.f;
            if (gy >= 0 && gy < HIN && gx >= 0 && gx < HIN) v = ip[gy * HIN + gx];
            stile[i] = v;
        }
        __syncthreads();
        float tv[16];
#pragma unroll
        for (int ky = 0; ky < 4; ky++)
#pragma unroll
            for (int kx = 0; kx < 4; kx++)
                tv[ky * 4 + kx] = stile[(2 * ty + ky) * 34 + 2 * tx + kx];
#pragma unroll
        for (int co = 0; co < 8; co++) {
            const float* wc = &swt[(co * 64 + ci) * 16];
            float a = acc[co];
#pragma unroll
            for (int k = 0; k < 16; k++) a += tv[k] * wc[k];
            acc[co] = a;
        }
    }
    int oy = ty0 + ty, ox = tx0 + tx;
    float* ob = out + (size_t)b * 64 * HOUT * HOUT + (size_t)(cog * 8) * HOUT * HOUT
                + (size_t)oy * HOUT + ox;
#pragma unroll
    for (int co = 0; co < 8; co++)
        ob[(size_t)co * HOUT * HOUT] = acc[co] + bias[cog * 8 + co];
}

// ================= fused (z + a*k) -> GroupNorm -> ReLU, single pass, HW = 1024*PER ======
template<int PER>
__global__ __launch_bounds__(256) void gnaxpy_kernel(const float* __restrict__ in1,
    const float* __restrict__ in2, float a, float* __restrict__ out,
    const float* __restrict__ w, const float* __restrict__ b) {
    int bc = blockIdx.x;
    int c = bc & 63;
    int tid = threadIdx.x;
    const float4* p1 = (const float4*)(in1 + (size_t)bc * 1024 * PER);
    const float4* p2 = (const float4*)(in2 + (size_t)bc * 1024 * PER);
    float4 v[PER];
    float s = 0.f, s2 = 0.f;
#pragma unroll
    for (int j = 0; j < PER; j++) {
        float4 a1 = p1[tid + 256 * j];
        float4 a2 = p2[tid + 256 * j];
        float4 xv;
        xv.x = fmaf(a, a2.x, a1.x);
        xv.y = fmaf(a, a2.y, a1.y);
        xv.z = fmaf(a, a2.z, a1.z);
        xv.w = fmaf(a, a2.w, a1.w);
        v[j] = xv;
        s += xv.x + xv.y + xv.z + xv.w;
        s2 += xv.x * xv.x + xv.y * xv.y + xv.z * xv.z + xv.w * xv.w;
    }
    __shared__ float rs[4], rs2[4];
#pragma unroll
    for (int off = 32; off > 0; off >>= 1) {
        s  += __shfl_down(s, off, 64);
        s2 += __shfl_down(s2, off, 64);
    }
    int lane = tid & 63, wv = tid >> 6;
    if (lane == 0) { rs[wv] = s; rs2[wv] = s2; }
    __syncthreads();
    if (tid == 0) {
        float ts = rs[0] + rs[1] + rs[2] + rs[3];
        float ts2 = rs2[0] + rs2[1] + rs2[2] + rs2[3];
        const float HW = 1024.f * PER;
        float mean = ts / HW;
        float var = ts2 / HW - mean * mean;
        rs[0] = mean;
        rs2[0] = rsqrtf(var + 1e-5f);
    }
    __syncthreads();
    float mean = rs[0], rstd = rs2[0];
    float sc = rstd * w[c];
    float sh = b[c] - mean * sc;
    float4* q = (float4*)(out + (size_t)bc * 1024 * PER);
#pragma unroll
    for (int j = 0; j < PER; j++) {
        float4 xv = v[j];
        float4 y;
        y.x = fmaxf(fmaf(xv.x, sc, sh), 0.f);
        y.y = fmaxf(fmaf(xv.y, sc, sh), 0.f);
        y.z = fmaxf(fmaf(xv.z, sc, sh), 0.f);
        y.w = fmaxf(fmaf(xv.w, sc, sh), 0.f);
        q[tid + 256 * j] = y;
    }
}

// ================= ODE conv 3x3 pad1, 65->64 (ch0 = const t); epilogue feeds kacc ========
// mode: 0: kacc=val; 1: kacc+=2*val; 2: kacc+=val; 3: no kacc op.
__global__ __launch_bounds__(256) void conv3ode_kernel(const float* __restrict__ in,
    const float* __restrict__ w, const float* __restrict__ bias, float t,
    float* __restrict__ out, float* __restrict__ kacc, int mode) {
    __shared__ float swt[8 * 65 * 12];   // stride-12 padded (48B, 16B-aligned) -> ds_read_b128
    __shared__ float stile[10 * 34];
    int tid = threadIdx.x;
    int b = blockIdx.z, cog = blockIdx.y;
    int y0 = blockIdx.x * 8;
    const float* wp = w + (size_t)cog * 8 * 65 * 9;
    for (int i = tid; i < 8 * 65 * 12; i += 256) {
        int cidx = i / 12, k = i - cidx * 12;
        swt[i] = (k < 9) ? wp[cidx * 9 + k] : 0.f;
    }
    int tx = tid & 31, ty = tid >> 5;
    float acc[8];
#pragma unroll
    for (int i = 0; i < 8; i++) acc[i] = 0.f;
    const float* ib = in + (size_t)b * 64 * 1024;
    for (int ci = 0; ci < 65; ci++) {
        __syncthreads();
        if (ci == 0) {
            for (int i = tid; i < 340; i += 256) {
                int r = i / 34, cc = i % 34;
                int gy = y0 - 1 + r, gx = cc - 1;
                stile[i] = (gy >= 0 && gy < 32 && gx >= 0 && gx < 32) ? t : 0.f;
            }
        } else {
            const float* ip = ib + (size_t)(ci - 1) * 1024;
            for (int i = tid; i < 340; i += 256) {
                int r = i / 34, cc = i % 34;
                int gy = y0 - 1 + r, gx = cc - 1;
                stile[i] = (gy >= 0 && gy < 32 && gx >= 0 && gx < 32) ? ip[gy * 32 + gx] : 0.f;
            }
        }
        __syncthreads();
        float tv[9];
#pragma unroll
        for (int ky = 0; ky < 3; ky++)
#pragma unroll
            for (int kx = 0; kx < 3; kx++)
                tv[ky * 3 + kx] = stile[(ty + ky) * 34 + tx + kx];
#pragma unroll
        for (int co = 0; co < 8; co++) {
            const float* wc = &swt[(co * 65 + ci) * 12];
            float a = acc[co];
#pragma unroll
            for (int k = 0; k < 9; k++) a += tv[k] * wc[k];
            acc[co] = a;
        }
    }
    int oy = y0 + ty;
    size_t base = (size_t)b * 64 * 1024 + (size_t)(cog * 8) * 1024 + (size_t)oy * 32 + tx;
#pragma unroll
    for (int co = 0; co < 8; co++) {
        size_t idx = base + (size_t)co * 1024;
        float val = acc[co] + bias[cog * 8 + co];
        out[idx] = val;
        if (mode == 0)      kacc[idx] = val;
        else if (mode == 1) kacc[idx] += 2.f * val;
        else if (mode == 2) kacc[idx] += val;
    }
}

// ================= z += c*kacc (final RK4 combine), float4 =================
__global__ __launch_bounds__(256) void zupd_kernel(float* __restrict__ z,
    const float* __restrict__ kacc, float cc, int n4) {
    int i = blockIdx.x * 256 + threadIdx.x;
    if (i < n4) {
        float4 zv = ((const float4*)z)[i];
        float4 kv = ((const float4*)kacc)[i];
        zv.x = fmaf(cc, kv.x, zv.x);
        zv.y = fmaf(cc, kv.y, zv.y);
        zv.z = fmaf(cc, kv.z, zv.z);
        zv.w = fmaf(cc, kv.w, zv.w);
        ((float4*)z)[i] = zv;
    }
}

// ================= head: GN + ReLU + GAP -> pooled[b*64+c] =================
__global__ __launch_bounds__(256) void headgap_kernel(const float* __restrict__ in,
    const float* __restrict__ w, const float* __restrict__ b, float* __restrict__ pooled) {
    int bc = blockIdx.x, c = bc & 63;
    int tid = threadIdx.x;
    const float4* p = (const float4*)(in + (size_t)bc * 1024);
    float4 xv = p[tid];
    float s = xv.x + xv.y + xv.z + xv.w;
    float s2 = xv.x * xv.x + xv.y * xv.y + xv.z * xv.z + xv.w * xv.w;
    __shared__ float rs[4], rs2[4];
#pragma unroll
    for (int off = 32; off > 0; off >>= 1) {
        s  += __shfl_down(s, off, 64);
        s2 += __shfl_down(s2, off, 64);
    }
    int lane = tid & 63, wv = tid >> 6;
    if (lane == 0) { rs[wv] = s; rs2[wv] = s2; }
    __syncthreads();
    if (tid == 0) {
        float ts = rs[0] + rs[1] + rs[2] + rs[3];
        float ts2 = rs2[0] + rs2[1] + rs2[2] + rs2[3];
        float mean = ts / 1024.f;
        float var = ts2 / 1024.f - mean * mean;
        rs[0] = mean;
        rs2[0] = rsqrtf(var + 1e-5f);
    }
    __syncthreads();
    float mean = rs[0], rstd = rs2[0];
    float sc = rstd * w[c];
    float sh = b[c] - mean * sc;
    float r = fmaxf(fmaf(xv.x, sc, sh), 0.f) + fmaxf(fmaf(xv.y, sc, sh), 0.f)
            + fmaxf(fmaf(xv.z, sc, sh), 0.f) + fmaxf(fmaf(xv.w, sc, sh), 0.f);
#pragma unroll
    for (int off = 32; off > 0; off >>= 1) r += __shfl_down(r, off, 64);
    __syncthreads();
    if (lane == 0) rs[wv] = r;
    __syncthreads();
    if (tid == 0) pooled[bc] = (rs[0] + rs[1] + rs[2] + rs[3]) / 1024.f;
}

// ================= out[b,j] = pooled[b,:] . W[j,:] + bias[j] =================
__global__ __launch_bounds__(256) void headfc_kernel(const float* __restrict__ pooled,
    const float* __restrict__ W, const float* __restrict__ bias, float* __restrict__ out) {
    int i = blockIdx.x * 256 + threadIdx.x;
    if (i < 640) {
        int b = i / 10, j = i % 10;
        float a = bias[j];
        const float* p = pooled + b * 64;
        const float* wj = W + j * 64;
#pragma unroll 8
        for (int c = 0; c < 64; c++) a += p[c] * wj[c];
        out[i] = a;
    }
}

extern "C" void kernel_launch(void* const* d_in, const int* in_sizes, int n_in,
                              void* d_out, int out_size, void* d_ws, size_t ws_size,
                              hipStream_t stream) {
    const float* x      = (const float*)d_in[0];
    const float* ds_w1  = (const float*)d_in[1];
    const float* ds_b1  = (const float*)d_in[2];
    const float* ds_n1w = (const float*)d_in[3];
    const float* ds_n1b = (const float*)d_in[4];
    const float* ds_w2  = (const float*)d_in[5];
    const float* ds_b2  = (const float*)d_in[6];
    const float* ds_n2w = (const float*)d_in[7];
    const float* ds_n2b = (const float*)d_in[8];
    const float* ds_w3  = (const float*)d_in[9];
    const float* ds_b3  = (const float*)d_in[10];
    const float* ode_w1 = (const float*)d_in[11];
    const float* ode_b1 = (const float*)d_in[12];
    const float* ode_n1w= (const float*)d_in[13];
    const float* ode_n1b= (const float*)d_in[14];
    const float* ode_w2 = (const float*)d_in[15];
    const float* ode_b2 = (const float*)d_in[16];
    const float* ode_n2w= (const float*)d_in[17];
    const float* ode_n2b= (const float*)d_in[18];
    const float* head_nw= (const float*)d_in[19];
    const float* head_nb= (const float*)d_in[20];
    const float* head_W = (const float*)d_in[21];
    const float* head_b = (const float*)d_in[22];

    const size_t NZ  = (size_t)BB * CC * 32 * 32;   // 4,194,304 floats (16 MB)
    float* ws = (float*)d_ws;
    float* z    = ws;                 // NZ
    float* R    = ws + NZ;            // 4*NZ shared region
    float* h2   = R;                  // [B,64,64,64] = 4*NZ, dead before ODE starts
    float* ktmp = R;                  // ODE aliases (h2 dead)
    float* kacc = R + NZ;
    float* u    = R + 2 * NZ;
    float* v    = R + 3 * NZ;
    float* gn1sc = ws + 5 * NZ;       // 4096
    float* gn1sh = gn1sc + 4096;      // 4096
    float* ps    = gn1sh + 4096;      // 64*8*64 = 32768
    float* ps2   = ps + 32768;        // 32768
    float* pooled= ps2 + 32768;       // 4096
    // total: 5*NZ + 77,824 floats  ~= 84.2 MB

    // ---- downsampler (h1 never materialized) ----
    conv1stats_kernel<<<dim3(8, BB), 256, 0, stream>>>(x, ds_w1, ds_b1, ps, ps2);
    gn1fin_kernel<<<16, 256, 0, stream>>>(ps, ps2, ds_n1w, ds_n1b, gn1sc, gn1sh);
    fusedconv2_kernel<<<dim3(16, 8, BB), 256, 0, stream>>>(x, ds_w1, ds_b1, gn1sc, gn1sh,
                                                           ds_w2, ds_b2, h2);
    gnaxpy_kernel<4><<<BB * CC, 256, 0, stream>>>(h2, h2, 0.f, h2, ds_n2w, ds_n2b);
    conv4s2_kernel<32><<<dim3(4, 8, BB), 256, 0, stream>>>(h2, ds_w3, ds_b3, z);

    // ---- ODE: 10 RK4 steps ----
    const int nz4 = (int)(NZ / 4);
    auto rhs = [&](float t, const float* kin, float a, float* kout, int mode) {
        // u = relu(gn(z + a*kin))
        gnaxpy_kernel<1><<<BB * CC, 256, 0, stream>>>(z, kin, a, u, ode_n1w, ode_n1b);
        conv3ode_kernel<<<dim3(4, 8, BB), 256, 0, stream>>>(u, ode_w1, ode_b1, t, v, kacc, 3);
        gnaxpy_kernel<1><<<BB * CC, 256, 0, stream>>>(v, v, 0.f, v, ode_n2w, ode_n2b);
        conv3ode_kernel<<<dim3(4, 8, BB), 256, 0, stream>>>(v, ode_w2, ode_b2, t, kout, kacc, mode);
    };
    for (int i = 0; i < 10; i++) {
        float t = 0.1f * (float)i;
        rhs(t,          z,    0.f,   ktmp, 0);   // k1: kacc = k1
        rhs(t + 0.05f,  ktmp, 0.05f, ktmp, 1);   // k2: kacc += 2*k2
        rhs(t + 0.05f,  ktmp, 0.05f, ktmp, 1);   // k3: kacc += 2*k3
        rhs(t + 0.1f,   ktmp, 0.1f,  ktmp, 2);   // k4: kacc += k4
        zupd_kernel<<<nz4 / 256, 256, 0, stream>>>(z, kacc, 0.1f / 6.0f, nz4);
    }

    // ---- head ----
    headgap_kernel<<<BB * CC, 256, 0, stream>>>(z, head_nw, head_nb, pooled);
    headfc_kernel<<<3, 256, 0, stream>>>(pooled, head_W, head_b, (float*)d_out);
}

// Round 3
// 5132.276 us; speedup vs baseline: 3.1012x; 3.1012x over previous
//
#include <hip/hip_runtime.h>

#define BB 64   // batch
#define CC 64   // channels

typedef __attribute__((ext_vector_type(8))) short short8;
typedef __attribute__((ext_vector_type(4))) short short4v;
typedef __attribute__((ext_vector_type(4))) float f32x4;

__device__ __forceinline__ float bf2f(unsigned short h) {
    unsigned int u = ((unsigned int)h) << 16;
    float f; __builtin_memcpy(&f, &u, 4); return f;
}
__device__ __forceinline__ unsigned short f2bf(float f) {
    unsigned int u; __builtin_memcpy(&u, &f, 4);
    u += 0x7fffu + ((u >> 16) & 1u);
    return (unsigned short)(u >> 16);
}

// ================= GN1 stats directly from x (recompute conv1) =================
__global__ __launch_bounds__(256) void conv1stats_kernel(const float* __restrict__ x,
    const float* __restrict__ w1, const float* __restrict__ b1,
    float* __restrict__ ps, float* __restrict__ ps2) {
    __shared__ float sw1[576];
    __shared__ float sb1[64];
    __shared__ float xs[10 * 130];
    int tid = threadIdx.x;
    int qq = blockIdx.x;
    int b = blockIdx.y;
    for (int i = tid; i < 576; i += 256) sw1[i] = w1[i];
    if (tid < 64) sb1[tid] = b1[tid];
    const float* xb = x + (size_t)b * 130 * 130;
    int c = tid >> 2, q = tid & 3;
    float s = 0.f, s2 = 0.f;
    for (int sidx = 0; sidx < 2; sidx++) {
        int row0 = (qq * 2 + sidx) * 8;
        __syncthreads();
        for (int i = tid; i < 1300; i += 256) xs[i] = xb[row0 * 130 + i];
        __syncthreads();
        const float* wc = &sw1[c * 9];
        float bc = sb1[c];
        for (int p = q; p < 1024; p += 4) {
            int y = p >> 7, xx = p & 127;
            float v = bc;
#pragma unroll
            for (int ky = 0; ky < 3; ky++)
#pragma unroll
                for (int kx = 0; kx < 3; kx++)
                    v += xs[(y + ky) * 130 + xx + kx] * wc[ky * 3 + kx];
            s += v; s2 += v * v;
        }
    }
    s  += __shfl_xor(s, 1, 64);  s  += __shfl_xor(s, 2, 64);
    s2 += __shfl_xor(s2, 1, 64); s2 += __shfl_xor(s2, 2, 64);
    if (q == 0) {
        ps [(b * 8 + qq) * 64 + c] = s;
        ps2[(b * 8 + qq) * 64 + c] = s2;
    }
}

__global__ __launch_bounds__(256) void gn1fin_kernel(const float* __restrict__ ps,
    const float* __restrict__ ps2, const float* __restrict__ n1w, const float* __restrict__ n1b,
    float* __restrict__ gn1sc, float* __restrict__ gn1sh) {
    int i = blockIdx.x * 256 + threadIdx.x;
    if (i >= BB * CC) return;
    int c = i & 63, b = i >> 6;
    float s = 0.f, s2 = 0.f;
#pragma unroll
    for (int qq = 0; qq < 8; qq++) {
        s  += ps [(b * 8 + qq) * 64 + c];
        s2 += ps2[(b * 8 + qq) * 64 + c];
    }
    float mean = s / 16384.f;
    float var = s2 / 16384.f - mean * mean;
    float rstd = rsqrtf(var + 1e-5f);
    float sc = rstd * n1w[c];
    gn1sc[i] = sc;
    gn1sh[i] = n1b[c] - mean * sc;
}

// ======== fused conv1 + GN1 + ReLU + conv4x4/s2 -> h2[B,64,64,64] bf16 NCHW ========
__global__ __launch_bounds__(256) void fusedconv2_kernel(const float* __restrict__ x,
    const float* __restrict__ w1, const float* __restrict__ b1,
    const float* __restrict__ gn1sc, const float* __restrict__ gn1sh,
    const float* __restrict__ w2, const float* __restrict__ bias2,
    unsigned short* __restrict__ out) {
    __shared__ float swt[8 * 64 * 16];
    __shared__ float sw1[576];
    __shared__ float sb1[64];
    __shared__ float ssc[64];
    __shared__ float ssh[64];
    __shared__ float xs[36 * 36];
    __shared__ float stile[34 * 35];   // padded stride 35: stride-2 reads -> 2-way (free)
    int tid = threadIdx.x;
    int b = blockIdx.z, cog = blockIdx.y, tile = blockIdx.x;
    int tx0 = (tile & 3) * 16, ty0 = (tile >> 2) * 16;
    const float* wp = w2 + (size_t)cog * 8 * 64 * 16;
    for (int i = tid; i < 8192; i += 256) swt[i] = wp[i];
    for (int i = tid; i < 576; i += 256) sw1[i] = w1[i];
    if (tid < 64) {
        sb1[tid] = b1[tid];
        ssc[tid] = gn1sc[b * 64 + tid];
        ssh[tid] = gn1sh[b * 64 + tid];
    }
    {
        const float* xb = x + (size_t)b * 130 * 130;
        for (int i = tid; i < 1296; i += 256) {
            int r = i / 36, cc = i % 36;
            int gr = 2 * ty0 - 1 + r, gc = 2 * tx0 - 1 + cc;
            xs[i] = (gr >= 0 && gr < 130 && gc >= 0 && gc < 130) ? xb[gr * 130 + gc] : 0.f;
        }
    }
    int tx = tid & 15, ty = tid >> 4;
    float acc[8];
#pragma unroll
    for (int i = 0; i < 8; i++) acc[i] = 0.f;
    __syncthreads();
    for (int ci = 0; ci < 64; ci++) {
        float csc = ssc[ci], csh = ssh[ci], cb = sb1[ci];
        const float* wc1 = &sw1[ci * 9];
        for (int i = tid; i < 1156; i += 256) {
            int r = i / 34, cc = i % 34;
            int gy = 2 * ty0 - 1 + r, gx = 2 * tx0 - 1 + cc;
            float v = 0.f;
            if (gy >= 0 && gy < 128 && gx >= 0 && gx < 128) {
                float sacc = cb;
#pragma unroll
                for (int ky = 0; ky < 3; ky++)
#pragma unroll
                    for (int kx = 0; kx < 3; kx++)
                        sacc += xs[(r + ky) * 36 + cc + kx] * wc1[ky * 3 + kx];
                v = fmaxf(fmaf(sacc, csc, csh), 0.f);
            }
            stile[r * 35 + cc] = v;
        }
        __syncthreads();
        float tv[16];
#pragma unroll
        for (int ky = 0; ky < 4; ky++)
#pragma unroll
            for (int kx = 0; kx < 4; kx++)
                tv[ky * 4 + kx] = stile[(2 * ty + ky) * 35 + 2 * tx + kx];
#pragma unroll
        for (int co = 0; co < 8; co++) {
            const float* wc = &swt[(co * 64 + ci) * 16];
            float a = acc[co];
#pragma unroll
            for (int k = 0; k < 16; k++) a += tv[k] * wc[k];
            acc[co] = a;
        }
        __syncthreads();
    }
    int oy = ty0 + ty, ox = tx0 + tx;
    unsigned short* ob = out + (size_t)b * 64 * 4096 + (size_t)(cog * 8) * 4096
                         + (size_t)oy * 64 + ox;
#pragma unroll
    for (int co = 0; co < 8; co++)
        ob[(size_t)co * 4096] = f2bf(acc[co] + bias2[cog * 8 + co]);
}

// ================= GN+ReLU in-place on bf16 NCHW tensor, HW=4096 =================
__global__ __launch_bounds__(256) void gnbf16_kernel(unsigned short* __restrict__ h,
    const float* __restrict__ w, const float* __restrict__ b) {
    int bc = blockIdx.x, c = bc & 63, tid = threadIdx.x;
    unsigned short* p = h + (size_t)bc * 4096;
    short8 d0 = ((short8*)p)[tid];
    short8 d1 = ((short8*)p)[tid + 256];
    float f0[8], f1[8];
    float s = 0.f, s2 = 0.f;
#pragma unroll
    for (int e = 0; e < 8; e++) {
        f0[e] = bf2f((unsigned short)d0[e]); s += f0[e]; s2 += f0[e] * f0[e];
        f1[e] = bf2f((unsigned short)d1[e]); s += f1[e]; s2 += f1[e] * f1[e];
    }
    __shared__ float rs[4], rs2[4];
#pragma unroll
    for (int off = 32; off > 0; off >>= 1) {
        s  += __shfl_down(s, off, 64);
        s2 += __shfl_down(s2, off, 64);
    }
    int lane = tid & 63, wv = tid >> 6;
    if (lane == 0) { rs[wv] = s; rs2[wv] = s2; }
    __syncthreads();
    if (tid == 0) {
        float ts = rs[0] + rs[1] + rs[2] + rs[3];
        float ts2 = rs2[0] + rs2[1] + rs2[2] + rs2[3];
        float mean = ts / 4096.f;
        float var = fmaxf(ts2 / 4096.f - mean * mean, 0.f);
        rs[0] = mean;
        rs2[0] = rsqrtf(var + 1e-5f);
    }
    __syncthreads();
    float mean = rs[0], rstd = rs2[0];
    float sc = rstd * w[c];
    float sh = b[c] - mean * sc;
#pragma unroll
    for (int e = 0; e < 8; e++) {
        d0[e] = (short)f2bf(fmaxf(fmaf(f0[e], sc, sh), 0.f));
        d1[e] = (short)f2bf(fmaxf(fmaf(f1[e], sc, sh), 0.f));
    }
    ((short8*)p)[tid] = d0;
    ((short8*)p)[tid + 256] = d1;
}

// ==== conv 4x4 stride2 pad1, 64->64, 64x64 -> 32x32; bf16 NCHW in; z fp32 NHWC +
// ==== zbf16 NHWC + per-(b,c) sums (slot) out ====
__global__ __launch_bounds__(256) void conv4s2_kernel(const unsigned short* __restrict__ in,
    const float* __restrict__ w, const float* __restrict__ bias,
    float* __restrict__ z, unsigned short* __restrict__ zb, float* __restrict__ sums) {
    const int HIN = 64;
    __shared__ float swt[8 * 64 * 16];
    __shared__ float stile[34 * 35];
    __shared__ float sra[4][8], srb[4][8];
    int tid = threadIdx.x;
    int b = blockIdx.z, cog = blockIdx.y, tileid = blockIdx.x;
    int tx0 = (tileid & 1) * 16;
    int ty0 = (tileid >> 1) * 16;
    const float* wp = w + (size_t)cog * 8 * 64 * 16;
    for (int i = tid; i < 8192; i += 256) swt[i] = wp[i];
    int tx = tid & 15, ty = tid >> 4;
    float acc[8];
#pragma unroll
    for (int i = 0; i < 8; i++) acc[i] = 0.f;
    const unsigned short* ib = in + (size_t)b * 64 * HIN * HIN;
    for (int ci = 0; ci < 64; ci++) {
        __syncthreads();
        const unsigned short* ip = ib + (size_t)ci * HIN * HIN;
        for (int i = tid; i < 1156; i += 256) {
            int r = i / 34, cc = i % 34;
            int gy = 2 * ty0 - 1 + r, gx = 2 * tx0 - 1 + cc;
            float v = 0.f;
            if (gy >= 0 && gy < HIN && gx >= 0 && gx < HIN) v = bf2f(ip[gy * HIN + gx]);
            stile[r * 35 + cc] = v;
        }
        __syncthreads();
        float tv[16];
#pragma unroll
        for (int ky = 0; ky < 4; ky++)
#pragma unroll
            for (int kx = 0; kx < 4; kx++)
                tv[ky * 4 + kx] = stile[(2 * ty + ky) * 35 + 2 * tx + kx];
#pragma unroll
        for (int co = 0; co < 8; co++) {
            const float* wc = &swt[(co * 64 + ci) * 16];
            float a = acc[co];
#pragma unroll
            for (int k = 0; k < 16; k++) a += tv[k] * wc[k];
            acc[co] = a;
        }
    }
    int oy = ty0 + ty, ox = tx0 + tx;
    size_t base = ((size_t)((b << 10) + oy * 32 + ox)) * 64 + cog * 8;
    float vals[8], fb[8];
    short8 ob;
#pragma unroll
    for (int co = 0; co < 8; co++) {
        vals[co] = acc[co] + bias[cog * 8 + co];
        unsigned short h = f2bf(vals[co]);
        ob[co] = (short)h;
        fb[co] = bf2f(h);
    }
    f32x4 zv0, zv1;
#pragma unroll
    for (int e = 0; e < 4; e++) { zv0[e] = vals[e]; zv1[e] = vals[4 + e]; }
    *(f32x4*)(z + base) = zv0;
    *(f32x4*)(z + base + 4) = zv1;
    *(short8*)(zb + base) = ob;
    // per-(b,co) stats of bf16(z)
    int lane = tid & 63, wv = tid >> 6;
#pragma unroll
    for (int co = 0; co < 8; co++) {
        float s = fb[co], s2 = fb[co] * fb[co];
#pragma unroll
        for (int off = 32; off > 0; off >>= 1) {
            s  += __shfl_down(s, off, 64);
            s2 += __shfl_down(s2, off, 64);
        }
        if (lane == 0) { sra[wv][co] = s; srb[wv][co] = s2; }
    }
    __syncthreads();
    if (tid < 8) {
        float s = sra[0][tid] + sra[1][tid] + sra[2][tid] + sra[3][tid];
        float s2 = srb[0][tid] + srb[1][tid] + srb[2][tid] + srb[3][tid];
        atomicAdd(&sums[b * 64 + cog * 8 + tid], s);
        atomicAdd(&sums[4096 + b * 64 + cog * 8 + tid], s2);
    }
}

// ================= weight prepack: fp32 OIHW -> bf16 A[64][576] (k=tap*64+ci) ========
__global__ __launch_bounds__(64) void prepack_kernel(const float* __restrict__ w1,
    const float* __restrict__ w2, unsigned short* __restrict__ Apack,
    float* __restrict__ Stab) {
    int set = blockIdx.y, co = blockIdx.x, t = threadIdx.x;
    const float* w = set ? w2 : w1;
    unsigned short* arow = Apack + ((size_t)set * 64 + co) * 576;
    for (int k = t; k < 576; k += 64) {
        int tap = k >> 6, ci = k & 63;
        arow[k] = f2bf(w[(co * 65 + ci + 1) * 9 + tap]);
    }
    if (t < 9) Stab[(set * 64 + co) * 9 + t] = w[(co * 65) * 9 + t];
}

// ==================== MFMA implicit-GEMM ODE conv (3x3 pad1, 64+t -> 64) ============
// in/out NHWC. mode: 3=first conv (out=bf16(val), stats); 0: kacc=val; 1: kacc+=2val;
// 2: kacc+=val (no uout/stats). modes 0/1 also write uout=bf16(z+aa*val) + stats.
__global__ __launch_bounds__(256) void convmfma_kernel(
    const unsigned short* __restrict__ uin, const float* __restrict__ sums_in,
    const float* __restrict__ gw, const float* __restrict__ gb,
    const unsigned short* __restrict__ Apack, const float* __restrict__ stab,
    const float* __restrict__ bias, float t, float aa, int mode,
    const float* __restrict__ zin, unsigned short* __restrict__ uout,
    float* __restrict__ kacc, float* __restrict__ sums_out)
{
    __shared__ unsigned short X[13056];              // 6 rows x 34 px x 64ci, swizzled
    __shared__ float ssc[64], ssh[64];
    __shared__ float tS[64], trow0[64], trow2[64], tcol0[64], tcol2[64];
    __shared__ float tc00[64], tc02[64], tc20[64], tc22[64];
    __shared__ float sred[4][64], s2red[4][64];

    int tid = threadIdx.x;
    int b = blockIdx.y, strip = blockIdx.x;
    int y0 = strip * 4;
    int lane = tid & 63, w = tid >> 6;
    int col = lane & 15, quad = lane >> 4;

    // phase 0: zero X + finalize input GN + t-channel tables
    {
        f32x4 zz = 0.f;
        for (int i = tid; i < 1632; i += 256) ((f32x4*)X)[i] = zz;
    }
    if (tid < 64) {
        int c = tid;
        float s = sums_in[b * 64 + c];
        float s2 = sums_in[4096 + b * 64 + c];
        float mean = s * (1.f / 1024.f);
        float var = fmaxf(s2 * (1.f / 1024.f) - mean * mean, 0.f);
        float sc = rsqrtf(var + 1e-5f) * gw[c];
        ssc[c] = sc;
        ssh[c] = gb[c] - mean * sc;
    } else if (tid < 128) {
        int co = tid - 64;
        float w0[9];
#pragma unroll
        for (int k = 0; k < 9; k++) w0[k] = stab[co * 9 + k] * t;
        tS[co] = bias[co] + w0[0]+w0[1]+w0[2]+w0[3]+w0[4]+w0[5]+w0[6]+w0[7]+w0[8];
        trow0[co] = w0[0] + w0[1] + w0[2];
        trow2[co] = w0[6] + w0[7] + w0[8];
        tcol0[co] = w0[0] + w0[3] + w0[6];
        tcol2[co] = w0[2] + w0[5] + w0[8];
        tc00[co] = w0[0]; tc02[co] = w0[2]; tc20[co] = w0[6]; tc22[co] = w0[8];
    }
    __syncthreads();

    // phase 1: stage input tile (normalize + relu on load), swizzled bf16
    {
        int sub = tid & 7, xc = tid >> 3;
        float scr[8], shr[8];
#pragma unroll
        for (int e = 0; e < 8; e++) { scr[e] = ssc[sub * 8 + e]; shr[e] = ssh[sub * 8 + e]; }
        for (int r = 0; r < 6; ++r) {
            int gy = y0 - 1 + r;
            if (gy < 0 || gy > 31) continue;
            int gp = (b << 10) + gy * 32 + xc;
            short8 d = *(const short8*)(uin + (size_t)gp * 64 + sub * 8);
            short8 o;
#pragma unroll
            for (int e = 0; e < 8; e++) {
                float f = bf2f((unsigned short)d[e]);
                o[e] = (short)f2bf(fmaxf(fmaf(f, scr[e], shr[e]), 0.f));
            }
            int ps = r * 34 + xc + 1;
            *(short8*)(X + ps * 64 + ((sub ^ (ps & 7)) * 8)) = o;
        }
    }
    __syncthreads();

    // phase 2: K-loop (K = 9 taps x 64 ci = 18 chunks of 32)
    f32x4 acc[4][2] = {};
    for (int tap = 0; tap < 9; ++tap) {
        int dy = tap / 3 - 1, dx = tap % 3 - 1;
        int ps0 = (w + 1 + dy) * 34 + col + dx + 1;
        int ps1 = ps0 + 16;
#pragma unroll
        for (int c2 = 0; c2 < 2; ++c2) {
            int kc = tap * 2 + c2;
            int ch = c2 * 4 + quad;
            short8 bb0 = *(const short8*)(X + ps0 * 64 + ((ch ^ (ps0 & 7)) * 8));
            short8 bb1 = *(const short8*)(X + ps1 * 64 + ((ch ^ (ps1 & 7)) * 8));
            const unsigned short* ap = Apack + (size_t)col * 576 + kc * 32 + quad * 8;
            short8 a0 = *(const short8*)(ap);
            short8 a1 = *(const short8*)(ap + 16 * 576);
            short8 a2 = *(const short8*)(ap + 32 * 576);
            short8 a3 = *(const short8*)(ap + 48 * 576);
            acc[0][0] = __builtin_amdgcn_mfma_f32_16x16x32_bf16(a0, bb0, acc[0][0], 0, 0, 0);
            acc[0][1] = __builtin_amdgcn_mfma_f32_16x16x32_bf16(a0, bb1, acc[0][1], 0, 0, 0);
            acc[1][0] = __builtin_amdgcn_mfma_f32_16x16x32_bf16(a1, bb0, acc[1][0], 0, 0, 0);
            acc[1][1] = __builtin_amdgcn_mfma_f32_16x16x32_bf16(a1, bb1, acc[1][1], 0, 0, 0);
            acc[2][0] = __builtin_amdgcn_mfma_f32_16x16x32_bf16(a2, bb0, acc[2][0], 0, 0, 0);
            acc[2][1] = __builtin_amdgcn_mfma_f32_16x16x32_bf16(a2, bb1, acc[2][1], 0, 0, 0);
            acc[3][0] = __builtin_amdgcn_mfma_f32_16x16x32_bf16(a3, bb0, acc[3][0], 0, 0, 0);
            acc[3][1] = __builtin_amdgcn_mfma_f32_16x16x32_bf16(a3, bb1, acc[3][1], 0, 0, 0);
        }
    }

    // phase 3: epilogue
    float sl[16], s2l[16];
#pragma unroll
    for (int i = 0; i < 16; i++) { sl[i] = 0.f; s2l[i] = 0.f; }
    int py = y0 + w;
    bool by0 = (py == 0), by1 = (py == 31);
#pragma unroll
    for (int mt = 0; mt < 4; ++mt) {
#pragma unroll
        for (int nt2 = 0; nt2 < 2; ++nt2) {
            int px = nt2 * 16 + col;
            int co0 = mt * 16 + quad * 4;
            bool bx0 = (px == 0), bx1 = (px == 31);
            float vout[4];
#pragma unroll
            for (int r = 0; r < 4; ++r) {
                int co = co0 + r;
                float val = acc[mt][nt2][r] + tS[co];
                if (by0) { val -= trow0[co]; if (bx0) val += tc00[co]; if (bx1) val += tc02[co]; }
                if (by1) { val -= trow2[co]; if (bx0) val += tc20[co]; if (bx1) val += tc22[co]; }
                if (bx0) val -= tcol0[co];
                if (bx1) val -= tcol2[co];
                vout[r] = val;
            }
            size_t base = ((size_t)((b << 10) + py * 32 + px)) * 64 + co0;
            if (mode == 3) {
                short4v o;
#pragma unroll
                for (int r = 0; r < 4; ++r) {
                    unsigned short h = f2bf(vout[r]);
                    o[r] = (short)h;
                    float f = bf2f(h);
                    sl[mt * 4 + r] += f; s2l[mt * 4 + r] += f * f;
                }
                *(short4v*)(uout + base) = o;
            } else if (mode == 2) {
                f32x4 kv = *(const f32x4*)(kacc + base);
#pragma unroll
                for (int r = 0; r < 4; ++r) kv[r] += vout[r];
                *(f32x4*)(kacc + base) = kv;
            } else {
                f32x4 zv = *(const f32x4*)(zin + base);
                f32x4 kv;
                if (mode == 1) {
                    kv = *(const f32x4*)(kacc + base);
#pragma unroll
                    for (int r = 0; r < 4; ++r) kv[r] += 2.f * vout[r];
                } else {
#pragma unroll
                    for (int r = 0; r < 4; ++r) kv[r] = vout[r];
                }
                *(f32x4*)(kacc + base) = kv;
                short4v o;
#pragma unroll
                for (int r = 0; r < 4; ++r) {
                    unsigned short h = f2bf(zv[r] + aa * vout[r]);
                    o[r] = (short)h;
                    float f = bf2f(h);
                    sl[mt * 4 + r] += f; s2l[mt * 4 + r] += f * f;
                }
                *(short4v*)(uout + base) = o;
            }
        }
    }
    if (mode != 2) {
#pragma unroll
        for (int idx = 0; idx < 16; ++idx) {
            float s = sl[idx], s2 = s2l[idx];
            s += __shfl_xor(s, 1, 64); s += __shfl_xor(s, 2, 64);
            s += __shfl_xor(s, 4, 64); s += __shfl_xor(s, 8, 64);
            s2 += __shfl_xor(s2, 1, 64); s2 += __shfl_xor(s2, 2, 64);
            s2 += __shfl_xor(s2, 4, 64); s2 += __shfl_xor(s2, 8, 64);
            if (col == 0) {
                int co = (idx >> 2) * 16 + quad * 4 + (idx & 3);
                sred[w][co] = s; s2red[w][co] = s2;
            }
        }
        __syncthreads();
        if (tid < 64) {
            float s = sred[0][tid] + sred[1][tid] + sred[2][tid] + sred[3][tid];
            float s2 = s2red[0][tid] + s2red[1][tid] + s2red[2][tid] + s2red[3][tid];
            atomicAdd(&sums_out[b * 64 + tid], s);
            atomicAdd(&sums_out[4096 + b * 64 + tid], s2);
        }
    }
}

// ========== z += (dt/6)*kacc; write z fp32 + zbf16; per-(b,c) raw sums ==========
__global__ __launch_bounds__(256) void zupd_kernel(float* __restrict__ z,
    const float* __restrict__ kacc, unsigned short* __restrict__ zb,
    float* __restrict__ sums) {
    __shared__ float sa[16][64], sa2[16][64];
    int b = blockIdx.x, tid = threadIdx.x;
    int cq = tid & 15, g = tid >> 4;
    const float cc6 = 0.1f / 6.0f;
    f32x4 s4 = 0.f, s24 = 0.f;
    for (int jj = 0; jj < 64; ++jj) {
        int p = g + 16 * jj;
        size_t idx = ((size_t)((b << 10) + p)) * 16 + cq;   // f32x4 units
        f32x4 zv = ((const f32x4*)z)[idx];
        f32x4 kv = ((const f32x4*)kacc)[idx];
        short4v o;
#pragma unroll
        for (int e = 0; e < 4; e++) {
            zv[e] = fmaf(cc6, kv[e], zv[e]);
            unsigned short h = f2bf(zv[e]);
            o[e] = (short)h;
            float f = bf2f(h);
            s4[e] += f; s24[e] += f * f;
        }
        ((f32x4*)z)[idx] = zv;
        *(short4v*)(zb + ((size_t)((b << 10) + p)) * 64 + cq * 4) = o;
    }
#pragma unroll
    for (int e = 0; e < 4; e++) { sa[g][cq * 4 + e] = s4[e]; sa2[g][cq * 4 + e] = s24[e]; }
    __syncthreads();
    if (tid < 64) {
        float s = 0.f, s2 = 0.f;
#pragma unroll
        for (int gg = 0; gg < 16; gg++) { s += sa[gg][tid]; s2 += sa2[gg][tid]; }
        sums[b * 64 + tid] = s;
        sums[4096 + b * 64 + tid] = s2;
    }
}

// ================= head: GN + ReLU + GAP from NHWC z =================
__global__ __launch_bounds__(256) void headgap_kernel(const float* __restrict__ z,
    const float* __restrict__ w, const float* __restrict__ b, float* __restrict__ pooled) {
    __shared__ float r1[4][64], r2[4][64];
    __shared__ float scs[64], shs[64];
    int bq = blockIdx.x, tid = threadIdx.x;
    int c = tid & 63, g = tid >> 6;
    float s = 0.f, s2 = 0.f;
    for (int p = g; p < 1024; p += 4) {
        float v = z[((size_t)((bq << 10) + p)) * 64 + c];
        s += v; s2 += v * v;
    }
    r1[g][c] = s; r2[g][c] = s2;
    __syncthreads();
    if (tid < 64) {
        float ts = r1[0][tid] + r1[1][tid] + r1[2][tid] + r1[3][tid];
        float ts2 = r2[0][tid] + r2[1][tid] + r2[2][tid] + r2[3][tid];
        float mean = ts / 1024.f;
        float var = fmaxf(ts2 / 1024.f - mean * mean, 0.f);
        float sc = rsqrtf(var + 1e-5f) * w[tid];
        scs[tid] = sc;
        shs[tid] = b[tid] - mean * sc;
    }
    __syncthreads();
    float sc = scs[c], sh = shs[c];
    float r = 0.f;
    for (int p = g; p < 1024; p += 4)
        r += fmaxf(fmaf(z[((size_t)((bq << 10) + p)) * 64 + c], sc, sh), 0.f);
    r1[g][c] = r;
    __syncthreads();
    if (tid < 64)
        pooled[bq * 64 + tid] = (r1[0][tid] + r1[1][tid] + r1[2][tid] + r1[3][tid]) / 1024.f;
}

__global__ __launch_bounds__(256) void headfc_kernel(const float* __restrict__ pooled,
    const float* __restrict__ W, const float* __restrict__ bias, float* __restrict__ out) {
    int i = blockIdx.x * 256 + threadIdx.x;
    if (i < 640) {
        int b = i / 10, j = i % 10;
        float a = bias[j];
        const float* p = pooled + b * 64;
        const float* wj = W + j * 64;
#pragma unroll 8
        for (int c = 0; c < 64; c++) a += p[c] * wj[c];
        out[i] = a;
    }
}

extern "C" void kernel_launch(void* const* d_in, const int* in_sizes, int n_in,
                              void* d_out, int out_size, void* d_ws, size_t ws_size,
                              hipStream_t stream) {
    const float* x      = (const float*)d_in[0];
    const float* ds_w1  = (const float*)d_in[1];
    const float* ds_b1  = (const float*)d_in[2];
    const float* ds_n1w = (const float*)d_in[3];
    const float* ds_n1b = (const float*)d_in[4];
    const float* ds_w2  = (const float*)d_in[5];
    const float* ds_b2  = (const float*)d_in[6];
    const float* ds_n2w = (const float*)d_in[7];
    const float* ds_n2b = (const float*)d_in[8];
    const float* ds_w3  = (const float*)d_in[9];
    const float* ds_b3  = (const float*)d_in[10];
    const float* ode_w1 = (const float*)d_in[11];
    const float* ode_b1 = (const float*)d_in[12];
    const float* ode_n1w= (const float*)d_in[13];
    const float* ode_n1b= (const float*)d_in[14];
    const float* ode_w2 = (const float*)d_in[15];
    const float* ode_b2 = (const float*)d_in[16];
    const float* ode_n2w= (const float*)d_in[17];
    const float* ode_n2b= (const float*)d_in[18];
    const float* head_nw= (const float*)d_in[19];
    const float* head_nb= (const float*)d_in[20];
    const float* head_W = (const float*)d_in[21];
    const float* head_b = (const float*)d_in[22];

    const size_t NZ = (size_t)BB * CC * 32 * 32;   // 4,194,304
    float* ws = (float*)d_ws;
    float*          z     = ws;                                   // [0, NZ) fp32 NHWC
    unsigned short* zb    = (unsigned short*)(ws + NZ);           // NZ bf16
    unsigned short* u     = (unsigned short*)(ws + NZ + NZ / 2);  // NZ bf16
    unsigned short* v     = (unsigned short*)(ws + 2 * NZ);       // NZ bf16
    float*          kacc  = ws + 5 * NZ / 2;                      // NZ fp32
    unsigned short* h2    = u;                                    // aliases u/v/kacc region (dead by ODE)
    float*          apf   = ws + 9 * NZ / 2;
    unsigned short* Apack = (unsigned short*)apf;                 // 2*64*576 bf16 = 36,864 fl
    float*          Stab  = apf + 36864;                          // 1,152
    float*          sums  = Stab + 1152;                          // 81 slots * 8192
    float*          ps    = sums + 81 * 8192;                     // 32,768
    float*          ps2   = ps + 32768;                           // 32,768
    float*          gn1sc = ps2 + 32768;                          // 4,096
    float*          gn1sh = gn1sc + 4096;                         // 4,096
    float*          pooled= gn1sh + 4096;                         // 4,096

    auto SUM = [&](int s) { return sums + (size_t)s * 8192; };
    auto SV = [&](int i, int j) { return 1 + i * 7 + j; };
    auto SU = [&](int i, int j) { return 1 + i * 7 + 4 + j; };
    auto ZS = [&](int i) { return 71 + i; };

    hipMemsetAsync(sums, 0, 81 * 8192 * sizeof(float), stream);
    prepack_kernel<<<dim3(64, 2), 64, 0, stream>>>(ode_w1, ode_w2, Apack, Stab);

    // ---- downsampler ----
    conv1stats_kernel<<<dim3(8, BB), 256, 0, stream>>>(x, ds_w1, ds_b1, ps, ps2);
    gn1fin_kernel<<<16, 256, 0, stream>>>(ps, ps2, ds_n1w, ds_n1b, gn1sc, gn1sh);
    fusedconv2_kernel<<<dim3(16, 8, BB), 256, 0, stream>>>(x, ds_w1, ds_b1, gn1sc, gn1sh,
                                                           ds_w2, ds_b2, h2);
    gnbf16_kernel<<<BB * CC, 256, 0, stream>>>(h2, ds_n2w, ds_n2b);
    conv4s2_kernel<<<dim3(4, 8, BB), 256, 0, stream>>>(h2, ds_w3, ds_b3, z, zb, SUM(0));

    // ---- ODE: 10 RK4 steps, all conv work on MFMA ----
    const unsigned short* AP1 = Apack;
    const unsigned short* AP2 = Apack + (size_t)64 * 576;
    const float* ST1 = Stab;
    const float* ST2 = Stab + 576;
    dim3 cgrid(8, BB);
    for (int i = 0; i < 10; i++) {
        float t0 = 0.1f * (float)i;
        int zslot = (i == 0) ? 0 : ZS(i - 1);
        // k1
        convmfma_kernel<<<cgrid, 256, 0, stream>>>(zb, SUM(zslot), ode_n1w, ode_n1b,
            AP1, ST1, ode_b1, t0, 0.f, 3, z, v, kacc, SUM(SV(i, 0)));
        convmfma_kernel<<<cgrid, 256, 0, stream>>>(v, SUM(SV(i, 0)), ode_n2w, ode_n2b,
            AP2, ST2, ode_b2, t0, 0.05f, 0, z, u, kacc, SUM(SU(i, 0)));
        // k2
        convmfma_kernel<<<cgrid, 256, 0, stream>>>(u, SUM(SU(i, 0)), ode_n1w, ode_n1b,
            AP1, ST1, ode_b1, t0 + 0.05f, 0.f, 3, z, v, kacc, SUM(SV(i, 1)));
        convmfma_kernel<<<cgrid, 256, 0, stream>>>(v, SUM(SV(i, 1)), ode_n2w, ode_n2b,
            AP2, ST2, ode_b2, t0 + 0.05f, 0.05f, 1, z, u, kacc, SUM(SU(i, 1)));
        // k3
        convmfma_kernel<<<cgrid, 256, 0, stream>>>(u, SUM(SU(i, 1)), ode_n1w, ode_n1b,
            AP1, ST1, ode_b1, t0 + 0.05f, 0.f, 3, z, v, kacc, SUM(SV(i, 2)));
        convmfma_kernel<<<cgrid, 256, 0, stream>>>(v, SUM(SV(i, 2)), ode_n2w, ode_n2b,
            AP2, ST2, ode_b2, t0 + 0.05f, 0.1f, 1, z, u, kacc, SUM(SU(i, 2)));
        // k4
        convmfma_kernel<<<cgrid, 256, 0, stream>>>(u, SUM(SU(i, 2)), ode_n1w, ode_n1b,
            AP1, ST1, ode_b1, t0 + 0.1f, 0.f, 3, z, v, kacc, SUM(SV(i, 3)));
        convmfma_kernel<<<cgrid, 256, 0, stream>>>(v, SUM(SV(i, 3)), ode_n2w, ode_n2b,
            AP2, ST2, ode_b2, t0 + 0.1f, 0.f, 2, z, u, kacc, SUM(SV(i, 3)));
        // z update + next-step stats
        zupd_kernel<<<BB, 256, 0, stream>>>(z, kacc, zb, SUM(ZS(i)));
    }

    // ---- head ----
    headgap_kernel<<<BB, 256, 0, stream>>>(z, head_nw, head_nb, pooled);
    headfc_kernel<<<3, 256, 0, stream>>>(pooled, head_W, head_b, (float*)d_out);
}

// Round 4
// 3076.701 us; speedup vs baseline: 5.1731x; 1.6681x over previous
//
#include <hip/hip_runtime.h>

#define BB 64   // batch
#define CC 64   // channels

typedef __attribute__((ext_vector_type(8))) short short8;
typedef __attribute__((ext_vector_type(4))) short short4v;
typedef __attribute__((ext_vector_type(4))) float f32x4;

__device__ __forceinline__ float bf2f(unsigned short h) {
    unsigned int u = ((unsigned int)h) << 16;
    float f; __builtin_memcpy(&f, &u, 4); return f;
}
__device__ __forceinline__ unsigned short f2bf(float f) {
    unsigned int u; __builtin_memcpy(&u, &f, 4);
    u += 0x7fffu + ((u >> 16) & 1u);
    return (unsigned short)(u >> 16);
}

// ================= GN1 stats directly from x (recompute conv1) =================
__global__ __launch_bounds__(256) void conv1stats_kernel(const float* __restrict__ x,
    const float* __restrict__ w1, const float* __restrict__ b1,
    float* __restrict__ ps, float* __restrict__ ps2) {
    __shared__ float sw1[576];
    __shared__ float sb1[64];
    __shared__ float xs[10 * 130];
    int tid = threadIdx.x;
    int qq = blockIdx.x;
    int b = blockIdx.y;
    for (int i = tid; i < 576; i += 256) sw1[i] = w1[i];
    if (tid < 64) sb1[tid] = b1[tid];
    const float* xb = x + (size_t)b * 130 * 130;
    int c = tid >> 2, q = tid & 3;
    float s = 0.f, s2 = 0.f;
    for (int sidx = 0; sidx < 2; sidx++) {
        int row0 = (qq * 2 + sidx) * 8;
        __syncthreads();
        for (int i = tid; i < 1300; i += 256) xs[i] = xb[row0 * 130 + i];
        __syncthreads();
        const float* wc = &sw1[c * 9];
        float bc = sb1[c];
        for (int p = q; p < 1024; p += 4) {
            int y = p >> 7, xx = p & 127;
            float v = bc;
#pragma unroll
            for (int ky = 0; ky < 3; ky++)
#pragma unroll
                for (int kx = 0; kx < 3; kx++)
                    v += xs[(y + ky) * 130 + xx + kx] * wc[ky * 3 + kx];
            s += v; s2 += v * v;
        }
    }
    s  += __shfl_xor(s, 1, 64);  s  += __shfl_xor(s, 2, 64);
    s2 += __shfl_xor(s2, 1, 64); s2 += __shfl_xor(s2, 2, 64);
    if (q == 0) {
        ps [(b * 8 + qq) * 64 + c] = s;
        ps2[(b * 8 + qq) * 64 + c] = s2;
    }
}

__global__ __launch_bounds__(256) void gn1fin_kernel(const float* __restrict__ ps,
    const float* __restrict__ ps2, const float* __restrict__ n1w, const float* __restrict__ n1b,
    float* __restrict__ gn1sc, float* __restrict__ gn1sh) {
    int i = blockIdx.x * 256 + threadIdx.x;
    if (i >= BB * CC) return;
    int c = i & 63, b = i >> 6;
    float s = 0.f, s2 = 0.f;
#pragma unroll
    for (int qq = 0; qq < 8; qq++) {
        s  += ps [(b * 8 + qq) * 64 + c];
        s2 += ps2[(b * 8 + qq) * 64 + c];
    }
    float mean = s / 16384.f;
    float var = s2 / 16384.f - mean * mean;
    float rstd = rsqrtf(var + 1e-5f);
    float sc = rstd * n1w[c];
    gn1sc[i] = sc;
    gn1sh[i] = n1b[c] - mean * sc;
}

// ===== weight prepack, chunk-major A: Apk[kc][co][32] bf16, coalesced wave reads =====
// sets: 0=ode_w1 (18 chunks), 1=ode_w2 (18), 2=ds_w2 (32), 3=ds_w3 (32)
__global__ __launch_bounds__(256) void prepack_kernel(const float* __restrict__ w1,
    const float* __restrict__ w2, const float* __restrict__ dw2,
    const float* __restrict__ dw3, unsigned short* __restrict__ Apk,
    float* __restrict__ Stab) {
    int set = blockIdx.y, kc = blockIdx.x, tid = threadIdx.x;
    int nchunk = (set < 2) ? 18 : 32;
    if (kc < nchunk) {
        const float* w = (set == 0) ? w1 : (set == 1) ? w2 : (set == 2) ? dw2 : dw3;
        size_t off = (set == 0) ? 0 : (set == 1) ? 36864 : (set == 2) ? 73728 : 139264;
        for (int e = tid; e < 2048; e += 256) {
            int co = e >> 5, j = e & 31;
            int k = kc * 32 + j;
            int ci = k & 63;
            int tap = k >> 6;
            float val;
            if (set < 2) val = w[(co * 65 + ci + 1) * 9 + tap];
            else         val = w[((co << 6) + ci) * 16 + tap];
            Apk[off + (size_t)kc * 2048 + e] = f2bf(val);
        }
    }
    if (set < 2 && kc == 0) {
        const float* w = set ? w2 : w1;
        for (int t = tid; t < 576; t += 256) {
            int co = t / 9, tap = t % 9;
            Stab[set * 576 + t] = w[(co * 65) * 9 + tap];
        }
    }
}

// ===== ds2mfma: x -> conv1 -> GN1 -> ReLU (in-register) -> conv4x4/s2 MFMA -> h2 =====
// h2: [B,64,64,64] NHWC bf16. grid (64 = 32 row-strips x 2 col-halves, B). K=1024.
__global__ __launch_bounds__(256) void ds2mfma_kernel(const float* __restrict__ x,
    const float* __restrict__ w1, const float* __restrict__ b1,
    const float* __restrict__ gn1sc, const float* __restrict__ gn1sh,
    const unsigned short* __restrict__ Apk, const float* __restrict__ bias2,
    unsigned short* __restrict__ h2, float* __restrict__ sums_out) {
    __shared__ unsigned short X[2 * 198 * 64];   // phase-split: [p][6*33][64ch], swizzled
    __shared__ float xs[8 * 68];
    __shared__ float sw1[576];
    __shared__ float sb1[64], ssc[64], ssh[64], sb2[64];
    __shared__ float sred[4][64], s2red[4][64];
    int tid = threadIdx.x;
    int b = blockIdx.y;
    int bx = blockIdx.x;
    int xh = bx & 1, sy = bx >> 1;               // col-half, row-strip
    int lane = tid & 63, w = tid >> 6;
    int colL = lane & 15, quad = lane >> 4;

    for (int i = tid; i < 576; i += 256) sw1[i] = w1[i];
    if (tid < 64) {
        sb1[tid] = b1[tid];
        ssc[tid] = gn1sc[b * 64 + tid];
        ssh[tid] = gn1sh[b * 64 + tid];
        sb2[tid] = bias2[tid];
    }
    {   // x halo: rows 4sy-1..4sy+6, cols 64xh-1..64xh+66
        const float* xb = x + (size_t)b * 130 * 130;
        for (int i = tid; i < 544; i += 256) {
            int r = i / 68, cc = i % 68;
            int xr = 4 * sy - 1 + r, xcg = 64 * xh - 1 + cc;
            xs[i] = (xr >= 0 && xr < 130 && xcg >= 0 && xcg < 130) ? xb[xr * 130 + xcg] : 0.f;
        }
    }
    __syncthreads();

    // compute h1 tile (6 rows x 66 cols x 64 ch) into swizzled phase-split X
    {
        int sub = tid & 7;
        float sbr[8], scr[8], shr[8];
#pragma unroll
        for (int e = 0; e < 8; e++) {
            int c = sub * 8 + e;
            sbr[e] = sb1[c]; scr[e] = ssc[c]; shr[e] = ssh[c];
        }
        for (int i = tid; i < 3168; i += 256) {
            int pidx = i >> 3;
            int ir = pidx / 66, ic = pidx - ir * 66;
            int gy = 4 * sy - 1 + ir, gxg = 64 * xh - 1 + ic;
            short8 o;
            if (gy >= 0 && gy < 128 && gxg >= 0 && gxg < 128) {
#pragma unroll
                for (int e = 0; e < 8; e++) {
                    int c = sub * 8 + e;
                    float v = sbr[e];
#pragma unroll
                    for (int ky = 0; ky < 3; ky++)
#pragma unroll
                        for (int kx = 0; kx < 3; kx++)
                            v += xs[(ir + ky) * 68 + ic + kx] * sw1[c * 9 + ky * 3 + kx];
                    o[e] = (short)f2bf(fmaxf(fmaf(v, scr[e], shr[e]), 0.f));
                }
            } else {
#pragma unroll
                for (int e = 0; e < 8; e++) o[e] = 0;
            }
            int p = ic & 1;
            int psx = ir * 33 + (ic >> 1);
            *(short8*)(X + ((p * 198 + psx) << 6) + ((sub ^ (psx & 7)) << 3)) = o;
        }
    }
    __syncthreads();

    // K-loop: 32 chunks (16 taps x 2), each wave: 1 n-tile (16 px), 4 m-tiles
    int l = w >> 1, oxb = (w & 1) * 16;
    int oxl = oxb + colL;                        // out col within half, 0..31
    f32x4 acc[4] = {};
    for (int kc = 0; kc < 32; ++kc) {
        int tap = kc >> 1;
        int ky = tap >> 2, kx = tap & 3;
        int chgrp = (kc & 1) * 4 + quad;
        int ir = 2 * l + ky;
        int p = kx & 1;
        int psx = ir * 33 + oxl + (kx >> 1);
        short8 bb = *(const short8*)(X + ((p * 198 + psx) << 6) + ((chgrp ^ (psx & 7)) << 3));
        const unsigned short* ap = Apk + (((kc << 6) + colL) << 5) + (quad << 3);
        short8 a0 = *(const short8*)(ap);
        short8 a1 = *(const short8*)(ap + 512);
        short8 a2 = *(const short8*)(ap + 1024);
        short8 a3 = *(const short8*)(ap + 1536);
        acc[0] = __builtin_amdgcn_mfma_f32_16x16x32_bf16(a0, bb, acc[0], 0, 0, 0);
        acc[1] = __builtin_amdgcn_mfma_f32_16x16x32_bf16(a1, bb, acc[1], 0, 0, 0);
        acc[2] = __builtin_amdgcn_mfma_f32_16x16x32_bf16(a2, bb, acc[2], 0, 0, 0);
        acc[3] = __builtin_amdgcn_mfma_f32_16x16x32_bf16(a3, bb, acc[3], 0, 0, 0);
    }

    // epilogue: h2 bf16 NHWC + GN2 partial sums
    float sl[16], s2l[16];
#pragma unroll
    for (int i = 0; i < 16; i++) { sl[i] = 0.f; s2l[i] = 0.f; }
    int oy = 2 * sy + l, oxg = xh * 32 + oxl;
#pragma unroll
    for (int mt = 0; mt < 4; ++mt) {
        int co0 = mt * 16 + quad * 4;
        size_t base = ((size_t)((b * 64 + oy) * 64 + oxg)) * 64 + co0;
        short4v o;
#pragma unroll
        for (int r = 0; r < 4; ++r) {
            unsigned short hh = f2bf(acc[mt][r] + sb2[co0 + r]);
            o[r] = (short)hh;
            float f = bf2f(hh);
            sl[mt * 4 + r] += f; s2l[mt * 4 + r] += f * f;
        }
        *(short4v*)(h2 + base) = o;
    }
#pragma unroll
    for (int idx = 0; idx < 16; ++idx) {
        float s = sl[idx], s2 = s2l[idx];
        s += __shfl_xor(s, 1, 64); s += __shfl_xor(s, 2, 64);
        s += __shfl_xor(s, 4, 64); s += __shfl_xor(s, 8, 64);
        s2 += __shfl_xor(s2, 1, 64); s2 += __shfl_xor(s2, 2, 64);
        s2 += __shfl_xor(s2, 4, 64); s2 += __shfl_xor(s2, 8, 64);
        if (colL == 0) {
            int co = (idx >> 2) * 16 + quad * 4 + (idx & 3);
            sred[w][co] = s; s2red[w][co] = s2;
        }
    }
    __syncthreads();
    if (tid < 64) {
        float s = sred[0][tid] + sred[1][tid] + sred[2][tid] + sred[3][tid];
        float s2 = s2red[0][tid] + s2red[1][tid] + s2red[2][tid] + s2red[3][tid];
        atomicAdd(&sums_out[b * 64 + tid], s);
        atomicAdd(&sums_out[4096 + b * 64 + tid], s2);
    }
}

// ===== ds3mfma: h2(bf16 NHWC) -> GN2+ReLU on load -> conv4x4/s2 MFMA -> z,zb,sums =====
// grid (16 row-strips, B). out 32x32.
__global__ __launch_bounds__(256) void ds3mfma_kernel(const unsigned short* __restrict__ h2,
    const float* __restrict__ sums_in, const float* __restrict__ gw, const float* __restrict__ gb,
    const unsigned short* __restrict__ Apk, const float* __restrict__ bias3,
    float* __restrict__ z, unsigned short* __restrict__ zb, float* __restrict__ sums_out) {
    __shared__ unsigned short X[2 * 198 * 64];
    __shared__ float ssc[64], ssh[64], sb3[64];
    __shared__ float sred[4][64], s2red[4][64];
    int tid = threadIdx.x;
    int b = blockIdx.y, sy = blockIdx.x;
    int lane = tid & 63, w = tid >> 6;
    int colL = lane & 15, quad = lane >> 4;

    if (tid < 64) {
        int c = tid;
        float s = sums_in[b * 64 + c];
        float s2 = sums_in[4096 + b * 64 + c];
        float mean = s * (1.f / 4096.f);
        float var = fmaxf(s2 * (1.f / 4096.f) - mean * mean, 0.f);
        float sc = rsqrtf(var + 1e-5f) * gw[c];
        ssc[c] = sc;
        ssh[c] = gb[c] - mean * sc;
        sb3[c] = bias3[c];
    }
    __syncthreads();
    {
        int sub = tid & 7;
        float scr[8], shr[8];
#pragma unroll
        for (int e = 0; e < 8; e++) { scr[e] = ssc[sub * 8 + e]; shr[e] = ssh[sub * 8 + e]; }
        for (int i = tid; i < 3168; i += 256) {
            int pidx = i >> 3;
            int ir = pidx / 66, ic = pidx - ir * 66;
            int gy = 4 * sy - 1 + ir, gx = ic - 1;
            short8 o;
            if (gy >= 0 && gy < 64 && gx >= 0 && gx < 64) {
                short8 d = *(const short8*)(h2 + ((size_t)((b * 64 + gy) * 64 + gx)) * 64 + sub * 8);
#pragma unroll
                for (int e = 0; e < 8; e++) {
                    float f = bf2f((unsigned short)d[e]);
                    o[e] = (short)f2bf(fmaxf(fmaf(f, scr[e], shr[e]), 0.f));
                }
            } else {
#pragma unroll
                for (int e = 0; e < 8; e++) o[e] = 0;
            }
            int p = ic & 1;
            int psx = ir * 33 + (ic >> 1);
            *(short8*)(X + ((p * 198 + psx) << 6) + ((sub ^ (psx & 7)) << 3)) = o;
        }
    }
    __syncthreads();

    int l = w >> 1, oxb = (w & 1) * 16;
    int oxl = oxb + colL;
    f32x4 acc[4] = {};
    for (int kc = 0; kc < 32; ++kc) {
        int tap = kc >> 1;
        int ky = tap >> 2, kx = tap & 3;
        int chgrp = (kc & 1) * 4 + quad;
        int ir = 2 * l + ky;
        int p = kx & 1;
        int psx = ir * 33 + oxl + (kx >> 1);
        short8 bb = *(const short8*)(X + ((p * 198 + psx) << 6) + ((chgrp ^ (psx & 7)) << 3));
        const unsigned short* ap = Apk + (((kc << 6) + colL) << 5) + (quad << 3);
        short8 a0 = *(const short8*)(ap);
        short8 a1 = *(const short8*)(ap + 512);
        short8 a2 = *(const short8*)(ap + 1024);
        short8 a3 = *(const short8*)(ap + 1536);
        acc[0] = __builtin_amdgcn_mfma_f32_16x16x32_bf16(a0, bb, acc[0], 0, 0, 0);
        acc[1] = __builtin_amdgcn_mfma_f32_16x16x32_bf16(a1, bb, acc[1], 0, 0, 0);
        acc[2] = __builtin_amdgcn_mfma_f32_16x16x32_bf16(a2, bb, acc[2], 0, 0, 0);
        acc[3] = __builtin_amdgcn_mfma_f32_16x16x32_bf16(a3, bb, acc[3], 0, 0, 0);
    }

    float sl[16], s2l[16];
#pragma unroll
    for (int i = 0; i < 16; i++) { sl[i] = 0.f; s2l[i] = 0.f; }
    int py = 2 * sy + l;
#pragma unroll
    for (int mt = 0; mt < 4; ++mt) {
        int co0 = mt * 16 + quad * 4;
        size_t base = ((size_t)((b << 10) + py * 32 + oxl)) * 64 + co0;
        f32x4 zv;
        short4v o;
#pragma unroll
        for (int r = 0; r < 4; ++r) {
            float val = acc[mt][r] + sb3[co0 + r];
            zv[r] = val;
            unsigned short hh = f2bf(val);
            o[r] = (short)hh;
            float f = bf2f(hh);
            sl[mt * 4 + r] += f; s2l[mt * 4 + r] += f * f;
        }
        *(f32x4*)(z + base) = zv;
        *(short4v*)(zb + base) = o;
    }
#pragma unroll
    for (int idx = 0; idx < 16; ++idx) {
        float s = sl[idx], s2 = s2l[idx];
        s += __shfl_xor(s, 1, 64); s += __shfl_xor(s, 2, 64);
        s += __shfl_xor(s, 4, 64); s += __shfl_xor(s, 8, 64);
        s2 += __shfl_xor(s2, 1, 64); s2 += __shfl_xor(s2, 2, 64);
        s2 += __shfl_xor(s2, 4, 64); s2 += __shfl_xor(s2, 8, 64);
        if (colL == 0) {
            int co = (idx >> 2) * 16 + quad * 4 + (idx & 3);
            sred[w][co] = s; s2red[w][co] = s2;
        }
    }
    __syncthreads();
    if (tid < 64) {
        float s = sred[0][tid] + sred[1][tid] + sred[2][tid] + sred[3][tid];
        float s2 = s2red[0][tid] + s2red[1][tid] + s2red[2][tid] + s2red[3][tid];
        atomicAdd(&sums_out[b * 64 + tid], s);
        atomicAdd(&sums_out[4096 + b * 64 + tid], s2);
    }
}

// ==================== MFMA implicit-GEMM ODE conv (3x3 pad1, 64+t -> 64) ============
// strip = 2 rows; grid (16, B). modes: 3: uout=bf16(val)+stats; 0: kacc=val,
// uout=bf16(z+aa*val)+stats; 1: kacc+=2*val, uout=bf16(z+aa*val)+stats;
// 2 (fused RK4 combine): z += aa*(kacc+val), uout(zb)=bf16(z)+stats.
__global__ __launch_bounds__(256) void convmfma_kernel(
    const unsigned short* __restrict__ uin, const float* __restrict__ sums_in,
    const float* __restrict__ gw, const float* __restrict__ gb,
    const unsigned short* __restrict__ Apk, const float* __restrict__ stab,
    const float* __restrict__ bias, float t, float aa, int mode,
    float* __restrict__ z, unsigned short* __restrict__ uout,
    float* __restrict__ kacc, float* __restrict__ sums_out)
{
    __shared__ unsigned short X[4 * 34 * 64];    // 8704 shorts, swizzled
    __shared__ float ssc[64], ssh[64];
    __shared__ float tS[64], trow0[64], trow2[64], tcol0[64], tcol2[64];
    __shared__ float tc00[64], tc02[64], tc20[64], tc22[64];
    __shared__ float sred[4][64], s2red[4][64];

    int tid = threadIdx.x;
    int b = blockIdx.y, strip = blockIdx.x;
    int y0 = strip * 2;
    int lane = tid & 63, w = tid >> 6;
    int colL = lane & 15, quad = lane >> 4;

    {   // zero X (pad cols / OOB rows stay zero)
        f32x4 zz = 0.f;
        for (int i = tid; i < 1088; i += 256) ((f32x4*)X)[i] = zz;
    }
    if (tid < 64) {
        int c = tid;
        float s = sums_in[b * 64 + c];
        float s2 = sums_in[4096 + b * 64 + c];
        float mean = s * (1.f / 1024.f);
        float var = fmaxf(s2 * (1.f / 1024.f) - mean * mean, 0.f);
        float sc = rsqrtf(var + 1e-5f) * gw[c];
        ssc[c] = sc;
        ssh[c] = gb[c] - mean * sc;
    } else if (tid < 128) {
        int co = tid - 64;
        float w0[9];
#pragma unroll
        for (int k = 0; k < 9; k++) w0[k] = stab[co * 9 + k] * t;
        tS[co] = bias[co] + w0[0]+w0[1]+w0[2]+w0[3]+w0[4]+w0[5]+w0[6]+w0[7]+w0[8];
        trow0[co] = w0[0] + w0[1] + w0[2];
        trow2[co] = w0[6] + w0[7] + w0[8];
        tcol0[co] = w0[0] + w0[3] + w0[6];
        tcol2[co] = w0[2] + w0[5] + w0[8];
        tc00[co] = w0[0]; tc02[co] = w0[2]; tc20[co] = w0[6]; tc22[co] = w0[8];
    }
    __syncthreads();

    {   // stage 4 input rows (GN+ReLU on load)
        int sub = tid & 7, xc = tid >> 3;
        float scr[8], shr[8];
#pragma unroll
        for (int e = 0; e < 8; e++) { scr[e] = ssc[sub * 8 + e]; shr[e] = ssh[sub * 8 + e]; }
#pragma unroll
        for (int r = 0; r < 4; ++r) {
            int gy = y0 - 1 + r;
            if (gy < 0 || gy > 31) continue;
            int gp = (b << 10) + gy * 32 + xc;
            short8 d = *(const short8*)(uin + (size_t)gp * 64 + sub * 8);
            short8 o;
#pragma unroll
            for (int e = 0; e < 8; e++) {
                float f = bf2f((unsigned short)d[e]);
                o[e] = (short)f2bf(fmaxf(fmaf(f, scr[e], shr[e]), 0.f));
            }
            int psx = r * 34 + xc + 1;
            *(short8*)(X + (psx << 6) + ((sub ^ (psx & 7)) << 3)) = o;
        }
    }
    __syncthreads();

    int l = w >> 1, oxb = (w & 1) * 16;
    int px = oxb + colL;
    f32x4 acc[4] = {};
    for (int kc = 0; kc < 18; ++kc) {
        int tap = kc >> 1;
        int dy = tap / 3, dx = tap % 3;
        int chgrp = (kc & 1) * 4 + quad;
        int psx = (l + dy) * 34 + px + dx;
        short8 bb = *(const short8*)(X + (psx << 6) + ((chgrp ^ (psx & 7)) << 3));
        const unsigned short* ap = Apk + (((kc << 6) + colL) << 5) + (quad << 3);
        short8 a0 = *(const short8*)(ap);
        short8 a1 = *(const short8*)(ap + 512);
        short8 a2 = *(const short8*)(ap + 1024);
        short8 a3 = *(const short8*)(ap + 1536);
        acc[0] = __builtin_amdgcn_mfma_f32_16x16x32_bf16(a0, bb, acc[0], 0, 0, 0);
        acc[1] = __builtin_amdgcn_mfma_f32_16x16x32_bf16(a1, bb, acc[1], 0, 0, 0);
        acc[2] = __builtin_amdgcn_mfma_f32_16x16x32_bf16(a2, bb, acc[2], 0, 0, 0);
        acc[3] = __builtin_amdgcn_mfma_f32_16x16x32_bf16(a3, bb, acc[3], 0, 0, 0);
    }

    // epilogue
    float sl[16], s2l[16];
#pragma unroll
    for (int i = 0; i < 16; i++) { sl[i] = 0.f; s2l[i] = 0.f; }
    int py = y0 + l;
    bool by0 = (py == 0), by1 = (py == 31);
    bool bx0 = (px == 0), bx1 = (px == 31);
#pragma unroll
    for (int mt = 0; mt < 4; ++mt) {
        int co0 = mt * 16 + quad * 4;
        float vout[4];
#pragma unroll
        for (int r = 0; r < 4; ++r) {
            int co = co0 + r;
            float val = acc[mt][r] + tS[co];
            if (by0) { val -= trow0[co]; if (bx0) val += tc00[co]; if (bx1) val += tc02[co]; }
            if (by1) { val -= trow2[co]; if (bx0) val += tc20[co]; if (bx1) val += tc22[co]; }
            if (bx0) val -= tcol0[co];
            if (bx1) val -= tcol2[co];
            vout[r] = val;
        }
        size_t base = ((size_t)((b << 10) + py * 32 + px)) * 64 + co0;
        if (mode == 3) {
            short4v o;
#pragma unroll
            for (int r = 0; r < 4; ++r) {
                unsigned short hh = f2bf(vout[r]);
                o[r] = (short)hh;
                float f = bf2f(hh);
                sl[mt * 4 + r] += f; s2l[mt * 4 + r] += f * f;
            }
            *(short4v*)(uout + base) = o;
        } else if (mode == 2) {
            f32x4 kv = *(const f32x4*)(kacc + base);
            f32x4 zv = *(const f32x4*)(z + base);
            short4v o;
#pragma unroll
            for (int r = 0; r < 4; ++r) {
                float zn = zv[r] + aa * (kv[r] + vout[r]);
                zv[r] = zn;
                unsigned short hh = f2bf(zn);
                o[r] = (short)hh;
                float f = bf2f(hh);
                sl[mt * 4 + r] += f; s2l[mt * 4 + r] += f * f;
            }
            *(f32x4*)(z + base) = zv;
            *(short4v*)(uout + base) = o;
        } else {
            f32x4 zv = *(const f32x4*)(z + base);
            f32x4 kv;
            if (mode == 1) {
                kv = *(const f32x4*)(kacc + base);
#pragma unroll
                for (int r = 0; r < 4; ++r) kv[r] += 2.f * vout[r];
            } else {
#pragma unroll
                for (int r = 0; r < 4; ++r) kv[r] = vout[r];
            }
            *(f32x4*)(kacc + base) = kv;
            short4v o;
#pragma unroll
            for (int r = 0; r < 4; ++r) {
                unsigned short hh = f2bf(zv[r] + aa * vout[r]);
                o[r] = (short)hh;
                float f = bf2f(hh);
                sl[mt * 4 + r] += f; s2l[mt * 4 + r] += f * f;
            }
            *(short4v*)(uout + base) = o;
        }
    }
#pragma unroll
    for (int idx = 0; idx < 16; ++idx) {
        float s = sl[idx], s2 = s2l[idx];
        s += __shfl_xor(s, 1, 64); s += __shfl_xor(s, 2, 64);
        s += __shfl_xor(s, 4, 64); s += __shfl_xor(s, 8, 64);
        s2 += __shfl_xor(s2, 1, 64); s2 += __shfl_xor(s2, 2, 64);
        s2 += __shfl_xor(s2, 4, 64); s2 += __shfl_xor(s2, 8, 64);
        if (colL == 0) {
            int co = (idx >> 2) * 16 + quad * 4 + (idx & 3);
            sred[w][co] = s; s2red[w][co] = s2;
        }
    }
    __syncthreads();
    if (tid < 64) {
        float s = sred[0][tid] + sred[1][tid] + sred[2][tid] + sred[3][tid];
        float s2 = s2red[0][tid] + s2red[1][tid] + s2red[2][tid] + s2red[3][tid];
        atomicAdd(&sums_out[b * 64 + tid], s);
        atomicAdd(&sums_out[4096 + b * 64 + tid], s2);
    }
}

// ================= head: GN + ReLU + GAP from NHWC z =================
__global__ __launch_bounds__(256) void headgap_kernel(const float* __restrict__ z,
    const float* __restrict__ w, const float* __restrict__ b, float* __restrict__ pooled) {
    __shared__ float r1[4][64], r2[4][64];
    __shared__ float scs[64], shs[64];
    int bq = blockIdx.x, tid = threadIdx.x;
    int c = tid & 63, g = tid >> 6;
    float s = 0.f, s2 = 0.f;
    for (int p = g; p < 1024; p += 4) {
        float v = z[((size_t)((bq << 10) + p)) * 64 + c];
        s += v; s2 += v * v;
    }
    r1[g][c] = s; r2[g][c] = s2;
    __syncthreads();
    if (tid < 64) {
        float ts = r1[0][tid] + r1[1][tid] + r1[2][tid] + r1[3][tid];
        float ts2 = r2[0][tid] + r2[1][tid] + r2[2][tid] + r2[3][tid];
        float mean = ts / 1024.f;
        float var = fmaxf(ts2 / 1024.f - mean * mean, 0.f);
        float sc = rsqrtf(var + 1e-5f) * w[tid];
        scs[tid] = sc;
        shs[tid] = b[tid] - mean * sc;
    }
    __syncthreads();
    float sc = scs[c], sh = shs[c];
    float r = 0.f;
    for (int p = g; p < 1024; p += 4)
        r += fmaxf(fmaf(z[((size_t)((bq << 10) + p)) * 64 + c], sc, sh), 0.f);
    r1[g][c] = r;
    __syncthreads();
    if (tid < 64)
        pooled[bq * 64 + tid] = (r1[0][tid] + r1[1][tid] + r1[2][tid] + r1[3][tid]) / 1024.f;
}

__global__ __launch_bounds__(256) void headfc_kernel(const float* __restrict__ pooled,
    const float* __restrict__ W, const float* __restrict__ bias, float* __restrict__ out) {
    int i = blockIdx.x * 256 + threadIdx.x;
    if (i < 640) {
        int b = i / 10, j = i % 10;
        float a = bias[j];
        const float* p = pooled + b * 64;
        const float* wj = W + j * 64;
#pragma unroll 8
        for (int c = 0; c < 64; c++) a += p[c] * wj[c];
        out[i] = a;
    }
}

extern "C" void kernel_launch(void* const* d_in, const int* in_sizes, int n_in,
                              void* d_out, int out_size, void* d_ws, size_t ws_size,
                              hipStream_t stream) {
    const float* x      = (const float*)d_in[0];
    const float* ds_w1  = (const float*)d_in[1];
    const float* ds_b1  = (const float*)d_in[2];
    const float* ds_n1w = (const float*)d_in[3];
    const float* ds_n1b = (const float*)d_in[4];
    const float* ds_w2  = (const float*)d_in[5];
    const float* ds_b2  = (const float*)d_in[6];
    const float* ds_n2w = (const float*)d_in[7];
    const float* ds_n2b = (const float*)d_in[8];
    const float* ds_w3  = (const float*)d_in[9];
    const float* ds_b3  = (const float*)d_in[10];
    const float* ode_w1 = (const float*)d_in[11];
    const float* ode_b1 = (const float*)d_in[12];
    const float* ode_n1w= (const float*)d_in[13];
    const float* ode_n1b= (const float*)d_in[14];
    const float* ode_w2 = (const float*)d_in[15];
    const float* ode_b2 = (const float*)d_in[16];
    const float* ode_n2w= (const float*)d_in[17];
    const float* ode_n2b= (const float*)d_in[18];
    const float* head_nw= (const float*)d_in[19];
    const float* head_nb= (const float*)d_in[20];
    const float* head_W = (const float*)d_in[21];
    const float* head_b = (const float*)d_in[22];

    const size_t NZ = (size_t)BB * CC * 32 * 32;   // 4,194,304
    float* ws = (float*)d_ws;
    float*          z     = ws;                                   // NZ fp32 NHWC
    unsigned short* zb    = (unsigned short*)(ws + NZ);           // NZ bf16
    unsigned short* u     = (unsigned short*)(ws + 3 * NZ / 2);   // NZ bf16
    unsigned short* v     = (unsigned short*)(ws + 2 * NZ);       // NZ bf16
    float*          kacc  = ws + 5 * NZ / 2;                      // NZ fp32
    unsigned short* h2    = u;   // [B,64,64,64] NHWC bf16 = 2*NZ floats, dead by ODE
    float*          apf   = ws + 7 * NZ / 2;
    unsigned short* Apk   = (unsigned short*)apf;                 // 204,800 shorts
    float*          Stab  = apf + 102400;                         // 1,152
    float*          sums  = Stab + 1152;                          // 82 slots * 8192
    float*          ps    = sums + 82 * 8192;                     // 32,768
    float*          ps2   = ps + 32768;                           // 32,768
    float*          gn1sc = ps2 + 32768;                          // 4,096
    float*          gn1sh = gn1sc + 4096;                         // 4,096
    float*          pooled= gn1sh + 4096;                         // 4,096

    auto SUM = [&](int s) { return sums + (size_t)s * 8192; };
    auto SV = [&](int i, int j) { return 1 + i * 7 + j; };
    auto SU = [&](int i, int j) { return 1 + i * 7 + 4 + j; };
    auto ZS = [&](int i) { return 71 + i; };
    const int H2S = 81;

    hipMemsetAsync(sums, 0, 82 * 8192 * sizeof(float), stream);
    prepack_kernel<<<dim3(32, 4), 256, 0, stream>>>(ode_w1, ode_w2, ds_w2, ds_w3, Apk, Stab);

    // ---- downsampler (all conv on MFMA; h1 recomputed in-register) ----
    conv1stats_kernel<<<dim3(8, BB), 256, 0, stream>>>(x, ds_w1, ds_b1, ps, ps2);
    gn1fin_kernel<<<16, 256, 0, stream>>>(ps, ps2, ds_n1w, ds_n1b, gn1sc, gn1sh);
    ds2mfma_kernel<<<dim3(64, BB), 256, 0, stream>>>(x, ds_w1, ds_b1, gn1sc, gn1sh,
        Apk + 73728, ds_b2, h2, SUM(H2S));
    ds3mfma_kernel<<<dim3(16, BB), 256, 0, stream>>>(h2, SUM(H2S), ds_n2w, ds_n2b,
        Apk + 139264, ds_b3, z, zb, SUM(0));

    // ---- ODE: 10 RK4 steps; zupd folded into mode-2 epilogue ----
    const unsigned short* AP1 = Apk;
    const unsigned short* AP2 = Apk + 36864;
    const float* ST1 = Stab;
    const float* ST2 = Stab + 576;
    const float c6 = 0.1f / 6.0f;
    dim3 cgrid(16, BB);
    for (int i = 0; i < 10; i++) {
        float t0 = 0.1f * (float)i;
        int zslot = (i == 0) ? 0 : ZS(i - 1);
        // k1
        convmfma_kernel<<<cgrid, 256, 0, stream>>>(zb, SUM(zslot), ode_n1w, ode_n1b,
            AP1, ST1, ode_b1, t0, 0.f, 3, z, v, kacc, SUM(SV(i, 0)));
        convmfma_kernel<<<cgrid, 256, 0, stream>>>(v, SUM(SV(i, 0)), ode_n2w, ode_n2b,
            AP2, ST2, ode_b2, t0, 0.05f, 0, z, u, kacc, SUM(SU(i, 0)));
        // k2
        convmfma_kernel<<<cgrid, 256, 0, stream>>>(u, SUM(SU(i, 0)), ode_n1w, ode_n1b,
            AP1, ST1, ode_b1, t0 + 0.05f, 0.f, 3, z, v, kacc, SUM(SV(i, 1)));
        convmfma_kernel<<<cgrid, 256, 0, stream>>>(v, SUM(SV(i, 1)), ode_n2w, ode_n2b,
            AP2, ST2, ode_b2, t0 + 0.05f, 0.05f, 1, z, u, kacc, SUM(SU(i, 1)));
        // k3
        convmfma_kernel<<<cgrid, 256, 0, stream>>>(u, SUM(SU(i, 1)), ode_n1w, ode_n1b,
            AP1, ST1, ode_b1, t0 + 0.05f, 0.f, 3, z, v, kacc, SUM(SV(i, 2)));
        convmfma_kernel<<<cgrid, 256, 0, stream>>>(v, SUM(SV(i, 2)), ode_n2w, ode_n2b,
            AP2, ST2, ode_b2, t0 + 0.05f, 0.1f, 1, z, u, kacc, SUM(SU(i, 2)));
        // k4
        convmfma_kernel<<<cgrid, 256, 0, stream>>>(u, SUM(SU(i, 2)), ode_n1w, ode_n1b,
            AP1, ST1, ode_b1, t0 + 0.1f, 0.f, 3, z, v, kacc, SUM(SV(i, 3)));
        convmfma_kernel<<<cgrid, 256, 0, stream>>>(v, SUM(SV(i, 3)), ode_n2w, ode_n2b,
            AP2, ST2, ode_b2, t0 + 0.1f, c6, 2, z, zb, kacc, SUM(ZS(i)));
    }

    // ---- head ----
    headgap_kernel<<<BB, 256, 0, stream>>>(z, head_nw, head_nb, pooled);
    headfc_kernel<<<3, 256, 0, stream>>>(pooled, head_W, head_b, (float*)d_out);
}